// Round 8
// baseline (333.968 us; speedup 1.0000x reference)
//
#include <hip/hip_runtime.h>

// RETRO chunked cross-attention, MI355X bf16 MFMA pipeline. Round 8:
//  - conv_bf16 ELIMINATED: kv256 reads e as f32 directly, converting during
//    A-staging (reg-stage: 4x global_load_dwordx4 one tile ahead -> cvt ->
//    2x swizzled ds_write_b128). Saves 192 MB HBM traffic (~30 us dispatch).
//  - B staging keeps global_load_lds (weights, L2-resident).
//  - vmcnt: per body issue A(T+2)x4 then B(T+2)x2; tile-top vmcnt(2) => A(T+1)
//    regs returned + all older staging landed. Even/odd named A-reg sets.
//  - Q/O GEMMs, attention: unchanged from round 6 (best total).

typedef __attribute__((ext_vector_type(8))) short short8;
typedef __attribute__((ext_vector_type(4))) float f32x4;
typedef unsigned short ushort_t;
typedef unsigned long long u64;

__device__ inline ushort_t f2bf(float f) {
  union { float f; unsigned int u; } v; v.f = f;
  unsigned int u = v.u;
  return (ushort_t)((u + 0x7fffu + ((u >> 16) & 1u)) >> 16);
}
__device__ inline float bf2f(ushort_t s) {
  union { unsigned int u; float f; } v; v.u = ((unsigned int)s) << 16;
  return v.f;
}

__device__ inline void gl_lds16(const void* g, void* l) {
  __builtin_amdgcn_global_load_lds(
      (const __attribute__((address_space(1))) unsigned int*)g,
      (__attribute__((address_space(3))) unsigned int*)l, 16, 0, 0);
}

// ---------------- 4x weight transpose + bf16 cast: WT[n][k] = W[k][n] -------
__global__ void transpose_w4(const float* __restrict__ W0, const float* __restrict__ W1,
                             const float* __restrict__ W2, const float* __restrict__ W3,
                             ushort_t* __restrict__ T0, ushort_t* __restrict__ T1,
                             ushort_t* __restrict__ T2, ushort_t* __restrict__ T3) {
  __shared__ float tile[32][33];
  const int z = blockIdx.z;
  const float* W = (z == 0) ? W0 : (z == 1) ? W1 : (z == 2) ? W2 : W3;
  ushort_t* WT   = (z == 0) ? T0 : (z == 1) ? T1 : (z == 2) ? T2 : T3;
  int k0 = blockIdx.x * 32, n0 = blockIdx.y * 32;
  int c = threadIdx.x & 31, r = threadIdx.x >> 5;  // r in 0..7
#pragma unroll
  for (int p = 0; p < 4; p++)
    tile[r + p * 8][c] = W[(size_t)(k0 + r + p * 8) * 1024 + n0 + c];
  __syncthreads();
#pragma unroll
  for (int p = 0; p < 4; p++)
    WT[(size_t)(n0 + r + p * 8) * 1024 + k0 + c] = f2bf(tile[c][r + p * 8]);
}

// ---------------- shifted LayerNorm -> bf16 query rows ----------------------
__global__ void ln_kernel(const float* __restrict__ h, const float* __restrict__ g,
                          const float* __restrict__ bb, ushort_t* __restrict__ hb) {
  int row = blockIdx.x;            // 0..8191
  int b = row >> 11, jj = row & 2047;
  int t = threadIdx.x;
  ushort_t* dst = hb + (size_t)row * 1024;
  if (jj >= 1985) {
    ((unsigned int*)dst)[t] = 0u;
    ((unsigned int*)dst)[t + 256] = 0u;
    return;
  }
  const float* src = h + ((size_t)(b << 11) + jj + 63) * 1024;
  f32x4 x = *(const f32x4*)&src[t * 4];
  float s = x[0] + x[1] + x[2] + x[3];
  float sq = x[0]*x[0] + x[1]*x[1] + x[2]*x[2] + x[3]*x[3];
#pragma unroll
  for (int off = 32; off > 0; off >>= 1) {
    s  += __shfl_xor(s, off);
    sq += __shfl_xor(sq, off);
  }
  __shared__ float red[8];
  if ((t & 63) == 0) { red[(t >> 6) * 2] = s; red[(t >> 6) * 2 + 1] = sq; }
  __syncthreads();
  float sum = red[0] + red[2] + red[4] + red[6];
  float sumsq = red[1] + red[3] + red[5] + red[7];
  float mu = sum * (1.f / 1024.f);
  float var = sumsq * (1.f / 1024.f) - mu * mu;
  float rs = rsqrtf(var + 1e-5f);
  f32x4 gg = *(const f32x4*)&g[t * 4];
  f32x4 bv = *(const f32x4*)&bb[t * 4];
  ushort_t o0 = f2bf((x[0] - mu) * rs * gg[0] + bv[0]);
  ushort_t o1 = f2bf((x[1] - mu) * rs * gg[1] + bv[1]);
  ushort_t o2 = f2bf((x[2] - mu) * rs * gg[2] + bv[2]);
  ushort_t o3 = f2bf((x[3] - mu) * rs * gg[3] + bv[3]);
  u64 pack = (u64)o0 | ((u64)o1 << 16) | ((u64)o2 << 32) | ((u64)o3 << 48);
  *(u64*)&dst[t * 4] = pack;
}

// ---------------- 128^2 GEMM, 2-phase fine schedule (r6) --------------------
// C[M x 1024] = A[M x 1024] @ BT^T + bias.
// EPI 0: bf16 out, pi-packed 8B stores (Q path).
// EPI 1: f32 out + residual + shifted store (O path).
template <int EPI>
__launch_bounds__(256, 2)
__global__ void gemm_bt(const ushort_t* __restrict__ A, const ushort_t* __restrict__ BT,
                        const float* __restrict__ bias, ushort_t* __restrict__ Cb,
                        float* __restrict__ Cf, const float* __restrict__ resid) {
  __shared__ __attribute__((aligned(16))) ushort_t lds[32768];  // 4 x (A 8KB + B 8KB)
  const int bid = blockIdx.x, cpx = gridDim.x >> 3;
  const int swz = (bid & 7) * cpx + (bid >> 3);
  const int tm = (swz >> 3) * 128, tn = (swz & 7) * 128;
  const int t = threadIdx.x, lane = t & 63, wv = t >> 6;
  const int wm = (wv >> 1) * 64, wn = (wv & 1) * 64;
  const int row16 = lane & 15, g = lane >> 4;

  const int c0 = t, c1 = t + 256;
  const int ra0 = c0 >> 2, sa0 = ((c0 & 3) ^ ((ra0 >> 1) & 3)) * 8;
  const int ra1 = c1 >> 2, sa1 = ((c1 & 3) ^ ((ra1 >> 1) & 3)) * 8;
  const ushort_t* Ag0 = A + (size_t)(tm + ra0) * 1024 + sa0;
  const ushort_t* Ag1 = A + (size_t)(tm + ra1) * 1024 + sa1;
  const ushort_t* Bg0 = BT + (size_t)(tn + ra0) * 1024 + sa0;
  const ushort_t* Bg1 = BT + (size_t)(tn + ra1) * 1024 + sa1;

#define STG_A(T) { ushort_t* L_ = lds + ((T) & 3) * 8192; const int k0_ = (T) * 32; \
    gl_lds16(Ag0 + k0_, L_ + c0 * 8); gl_lds16(Ag1 + k0_, L_ + c1 * 8); }
#define STG_B(T) { ushort_t* L_ = lds + ((T) & 3) * 8192; const int k0_ = (T) * 32; \
    gl_lds16(Bg0 + k0_, L_ + 4096 + c0 * 8); gl_lds16(Bg1 + k0_, L_ + 4096 + c1 * 8); }

  int aoff[4], boff[4];
#pragma unroll
  for (int m = 0; m < 4; m++) {
    int ra = wm + m * 16 + row16;
    aoff[m] = ra * 32 + (g ^ ((ra >> 1) & 3)) * 8;
  }
#pragma unroll
  for (int n = 0; n < 4; n++) {
    int rb = wn + n * 16 + row16;
    boff[n] = 4096 + rb * 32 + (g ^ ((rb >> 1) & 3)) * 8;
  }

  f32x4 acc[4][4] = {};
  STG_A(0); STG_B(0); STG_A(1); STG_B(1);
  for (int T = 0; T < 32; ++T) {
    const ushort_t* Lb = lds + (T & 3) * 8192;
    if (T < 31) { asm volatile("s_waitcnt vmcnt(4)" ::: "memory"); }
    else        { asm volatile("s_waitcnt vmcnt(0)" ::: "memory"); }
    __builtin_amdgcn_s_barrier();
    short8 af0, af1;
    short8 bfv[4];
    // ---- phase 0: read B all + A[0..1], stage A-half of T+2, MFMA m0-1 ----
#pragma unroll
    for (int n = 0; n < 4; n++) bfv[n] = *(const short8*)&Lb[boff[n]];
    af0 = *(const short8*)&Lb[aoff[0]];
    af1 = *(const short8*)&Lb[aoff[1]];
    if (T < 30) STG_A(T + 2);
    __builtin_amdgcn_s_barrier();
    asm volatile("s_waitcnt lgkmcnt(0)" ::: "memory");
    __builtin_amdgcn_sched_barrier(0);
    __builtin_amdgcn_s_setprio(1);
#pragma unroll
    for (int n = 0; n < 4; n++) {
      acc[0][n] = __builtin_amdgcn_mfma_f32_16x16x32_bf16(af0, bfv[n], acc[0][n], 0, 0, 0);
      acc[1][n] = __builtin_amdgcn_mfma_f32_16x16x32_bf16(af1, bfv[n], acc[1][n], 0, 0, 0);
    }
    __builtin_amdgcn_s_setprio(0);
    __builtin_amdgcn_s_barrier();
    // ---- phase 1: read A[2..3], stage B-half of T+2, MFMA m2-3 ----
    af0 = *(const short8*)&Lb[aoff[2]];
    af1 = *(const short8*)&Lb[aoff[3]];
    if (T < 30) STG_B(T + 2);
    __builtin_amdgcn_s_barrier();
    asm volatile("s_waitcnt lgkmcnt(0)" ::: "memory");
    __builtin_amdgcn_sched_barrier(0);
    __builtin_amdgcn_s_setprio(1);
#pragma unroll
    for (int n = 0; n < 4; n++) {
      acc[2][n] = __builtin_amdgcn_mfma_f32_16x16x32_bf16(af0, bfv[n], acc[2][n], 0, 0, 0);
      acc[3][n] = __builtin_amdgcn_mfma_f32_16x16x32_bf16(af1, bfv[n], acc[3][n], 0, 0, 0);
    }
    __builtin_amdgcn_s_setprio(0);
  }
#undef STG_A
#undef STG_B

  const int cr = g * 4, cc = row16;
  if (EPI == 0) {
    const int cb = tn + wn;  // 64-col strip base
    float bsv[4];
#pragma unroll
    for (int n = 0; n < 4; n++) bsv[n] = bias[cb + n * 16 + cc];
#pragma unroll
    for (int m = 0; m < 4; m++) {
      int rbase = tm + wm + m * 16 + cr;
#pragma unroll
      for (int j = 0; j < 4; j++) {
        u64 pack = (u64)f2bf(acc[m][0][j] + bsv[0])
                 | ((u64)f2bf(acc[m][1][j] + bsv[1]) << 16)
                 | ((u64)f2bf(acc[m][2][j] + bsv[2]) << 32)
                 | ((u64)f2bf(acc[m][3][j] + bsv[3]) << 48);
        *(u64*)&Cb[(size_t)(rbase + j) * 1024 + cb + cc * 4] = pack;
      }
    }
  } else {
#pragma unroll
    for (int m = 0; m < 4; m++) {
#pragma unroll
      for (int n = 0; n < 4; n++) {
        int col = tn + wn + n * 16 + cc;
        float bsv = bias[col];
#pragma unroll
        for (int j = 0; j < 4; j++) {
          int rg = tm + wm + m * 16 + cr + j;
          float v = acc[m][n][j] + bsv;
          int b = rg >> 11, jj = rg & 2047;
          if (jj < 1985) {
            size_t oi = ((size_t)(b << 11) + jj + 63) * 1024 + col;
            Cf[oi] = v + resid[oi];
          }
        }
      }
    }
  }
}

// ---------------- KV projection: 256x256 tile, fused f32->bf16 A-staging ----
// C[32768 x 2048] = cast_bf16(Af32) @ [WkT|WvT]^T, pi-packed split-write.
// A: reg-staged (4x dwordx4 f32 one tile ahead -> cvt -> 2x ds_write_b128).
// B: global_load_lds. Issue order per body: A(T+2)x4 then B(T+2)x2 =>
// tile-top vmcnt(2) guarantees A(T+1) regs + all older staging landed.
__launch_bounds__(512, 2)
__global__ void gemm_kv256(const float* __restrict__ Af, const ushort_t* __restrict__ BT,
                           const float* __restrict__ bk, const float* __restrict__ bv,
                           ushort_t* __restrict__ Ko, ushort_t* __restrict__ Vo) {
  __shared__ __attribute__((aligned(16))) ushort_t lds[65536];  // 4 x (A 16KB + B 16KB)
  const int bid = blockIdx.x;                    // 1024 blocks, %8==0 -> bijective swizzle
  const int swz = (bid & 7) * 128 + (bid >> 3);  // XCD chunk swizzle
  const int tm = (swz >> 3) * 256, tn = (swz & 7) * 256;
  const int t = threadIdx.x, lane = t & 63, wv = t >> 6;
  const int wm = wv >> 2, wn = wv & 3;           // 2M x 4N wave grid
  const int row16 = lane & 15, g = lane >> 4;

  // ---- A (f32) global pointers: linear, chunk t covers row t>>2, cols (t&3)*8..+7
  const int rcA = t >> 2, cgA = (t & 3) * 8;
  const float* Ar0 = Af + (size_t)(tm + rcA) * 1024 + cgA;
  const float* Ar1 = Ar0 + (size_t)128 * 1024;
  // LDS write offsets (bf16 elems), swizzled identically to frag reads.
  const int scA = ((t & 3) ^ ((rcA >> 1) & 3)) * 8;
  const int wofA0 = rcA * 32 + scA;            // rows 0..127
  const int wofA1 = (128 + rcA) * 32 + scA;    // rows 128..255 (same slot xor)

  // ---- B (bf16 weights): gl_lds with pre-swizzled source (as before)
  const int d1 = t + 512;
  const int rb0 = t >> 2, sb0 = ((t & 3) ^ ((rb0 >> 1) & 3)) * 8;
  const int rb1 = d1 >> 2, sb1 = ((d1 & 3) ^ ((rb1 >> 1) & 3)) * 8;
  const ushort_t* Bg0 = BT + (size_t)(tn + rb0) * 1024 + sb0;
  const ushort_t* Bg1 = BT + (size_t)(tn + rb1) * 1024 + sb1;

#define LOADA(T, S) { const int k0_ = (T) * 32;                                \
    S[0] = *(const f32x4*)(Ar0 + k0_);     S[1] = *(const f32x4*)(Ar0 + k0_ + 4); \
    S[2] = *(const f32x4*)(Ar1 + k0_);     S[3] = *(const f32x4*)(Ar1 + k0_ + 4); }
#define WRITEA(T, S) { ushort_t* L_ = lds + ((T) & 3) * 16384;                 \
    short8 w0_, w1_;                                                           \
    _Pragma("unroll") for (int i_ = 0; i_ < 4; i_++) {                         \
      w0_[i_] = (short)f2bf(S[0][i_]); w0_[4 + i_] = (short)f2bf(S[1][i_]);    \
      w1_[i_] = (short)f2bf(S[2][i_]); w1_[4 + i_] = (short)f2bf(S[3][i_]); }  \
    *(short8*)&L_[wofA0] = w0_; *(short8*)&L_[wofA1] = w1_; }
#define STGB(T) { ushort_t* L_ = lds + ((T) & 3) * 16384; const int k0_ = (T) * 32; \
    gl_lds16(Bg0 + k0_, L_ + 8192 + t * 8); gl_lds16(Bg1 + k0_, L_ + 8192 + d1 * 8); }

  int aoff[8], boff[4];
#pragma unroll
  for (int m = 0; m < 8; m++) {
    int ra = wm * 128 + m * 16 + row16;
    aoff[m] = ra * 32 + (g ^ ((ra >> 1) & 3)) * 8;
  }
#pragma unroll
  for (int n = 0; n < 4; n++) {
    int rb = wn * 64 + n * 16 + row16;
    boff[n] = 8192 + rb * 32 + (g ^ ((rb >> 1) & 3)) * 8;
  }

  f32x4 aE[4], aO[4];
  f32x4 acc[8][4] = {};

  // prologue: A0,B0,A1,B1; wait A0+B0; write A0.
  LOADA(0, aE); STGB(0); LOADA(1, aO); STGB(1);
  asm volatile("s_waitcnt vmcnt(6)" ::: "memory");   // newest 6 = A1(4)+B1(2)
  WRITEA(0, aE);
  asm volatile("s_waitcnt lgkmcnt(0)" ::: "memory");

  // body T: vmcnt(VMC); barrier; ph0{read B+A0-3, write A(T+1), load A(T+2)};
  //         barrier; lgkm0; MFMA m0-3; barrier;
  //         ph1{read A4-7, stgB(T+2)}; barrier; lgkm0; MFMA m4-7.
#define KV_BODY(T, aCur, aNxt, VMC, DOST, DOWR)                               \
  { asm volatile("s_waitcnt vmcnt(" #VMC ")" ::: "memory");                   \
    __builtin_amdgcn_s_barrier();                                             \
    const ushort_t* Lb = lds + ((T) & 3) * 16384;                             \
    short8 af_[4], bf_[4];                                                    \
    _Pragma("unroll")                                                         \
    for (int n = 0; n < 4; n++) bf_[n] = *(const short8*)&Lb[boff[n]];        \
    _Pragma("unroll")                                                         \
    for (int m = 0; m < 4; m++) af_[m] = *(const short8*)&Lb[aoff[m]];        \
    if (DOWR) { WRITEA((T) + 1, aCur); }                                      \
    if (DOST) { LOADA((T) + 2, aNxt); }                                       \
    __builtin_amdgcn_s_barrier();                                             \
    asm volatile("s_waitcnt lgkmcnt(0)" ::: "memory");                        \
    __builtin_amdgcn_sched_barrier(0);                                        \
    __builtin_amdgcn_s_setprio(1);                                            \
    _Pragma("unroll")                                                         \
    for (int m = 0; m < 4; m++)                                               \
      _Pragma("unroll")                                                       \
      for (int n = 0; n < 4; n++)                                             \
        acc[m][n] = __builtin_amdgcn_mfma_f32_16x16x32_bf16(af_[m], bf_[n], acc[m][n], 0, 0, 0); \
    __builtin_amdgcn_s_setprio(0);                                            \
    __builtin_amdgcn_s_barrier();                                             \
    _Pragma("unroll")                                                         \
    for (int m = 0; m < 4; m++) af_[m] = *(const short8*)&Lb[aoff[4 + m]];    \
    if (DOST) { STGB((T) + 2); }                                              \
    __builtin_amdgcn_s_barrier();                                             \
    asm volatile("s_waitcnt lgkmcnt(0)" ::: "memory");                        \
    __builtin_amdgcn_sched_barrier(0);                                        \
    __builtin_amdgcn_s_setprio(1);                                            \
    _Pragma("unroll")                                                         \
    for (int m = 0; m < 4; m++)                                               \
      _Pragma("unroll")                                                       \
      for (int n = 0; n < 4; n++)                                             \
        acc[4 + m][n] = __builtin_amdgcn_mfma_f32_16x16x32_bf16(af_[m], bf_[n], acc[4 + m][n], 0, 0, 0); \
    __builtin_amdgcn_s_setprio(0); }

  for (int it = 0; it < 15; ++it) {
    const int T0 = 2 * it;
    KV_BODY(T0,     aO, aE, 2, 1, 1);   // writes A(T0+1), loads A(T0+2), stages B(T0+2)
    KV_BODY(T0 + 1, aE, aO, 2, 1, 1);
  }
  KV_BODY(30, aO, aE, 2, 0, 1);  // writes A(31); no new loads
  KV_BODY(31, aE, aO, 0, 0, 0);  // final tile; drain all
#undef KV_BODY
#undef LOADA
#undef WRITEA
#undef STGB

  // pi-packed epilogue: orig col (cb64 + n*16 + row16) stored at cb64 + row16*4 + n.
  const bool isV = (tn >= 1024);
  const float* bias = isV ? bv : bk;
  ushort_t* Out = isV ? Vo : Ko;
  const int cb64 = (isV ? tn - 1024 : tn) + wn * 64;
  float bsv[4];
#pragma unroll
  for (int n = 0; n < 4; n++) bsv[n] = bias[cb64 + n * 16 + row16];
#pragma unroll
  for (int m = 0; m < 8; m++) {
    int rbase = tm + wm * 128 + m * 16 + g * 4;
#pragma unroll
    for (int j = 0; j < 4; j++) {
      u64 pack = (u64)f2bf(acc[m][0][j] + bsv[0])
               | ((u64)f2bf(acc[m][1][j] + bsv[1]) << 16)
               | ((u64)f2bf(acc[m][2][j] + bsv[2]) << 32)
               | ((u64)f2bf(acc[m][3][j] + bsv[3]) << 48);
      *(u64*)&Out[(size_t)(rbase + j) * 1024 + cb64 + row16 * 4] = pack;
    }
  }
}

// ---------------- attention: one block per (b,c,h) --------------------------
// Q,K,V arrive with pi-permuted d-columns (within each head's 64 cols).
// QK^T invariant; V transpose applies pi^-1 so PV output is natural.
__launch_bounds__(256, 2)
__global__ void attn_kernel(const ushort_t* __restrict__ Q, const ushort_t* __restrict__ Kb,
                            const ushort_t* __restrict__ Vb, ushort_t* __restrict__ Ob) {
  __shared__ __attribute__((aligned(16))) ushort_t R0[20480];     // Qs[4096]+Ks[16384]
  __shared__ __attribute__((aligned(16))) ushort_t Vt[64 * 264];  // V^T, padded stride
  ushort_t* Qs = R0;
  ushort_t* Ks = R0 + 4096;
  ushort_t* Sp = R0;  // bf16 S/P [64][264] overlays Qs+Ks after QK^T

  const int hh = blockIdx.x, cch = blockIdx.y, b = blockIdx.z;
  const int t = threadIdx.x, lane = t & 63, wv = t >> 6;
  const size_t qbase = ((size_t)(b * 32 + cch) * 64) * 1024 + hh * 64;
  const size_t kvbase = ((size_t)(b * 32 + cch) * 256) * 1024 + hh * 64;

  {
    int ch = t, r = ch >> 3, gq = (ch & 7) ^ (r & 7);
    gl_lds16(Q + qbase + (size_t)r * 1024 + gq * 8, &Qs[ch * 8]);
    ch = t + 256; r = ch >> 3; gq = (ch & 7) ^ (r & 7);
    gl_lds16(Q + qbase + (size_t)r * 1024 + gq * 8, &Qs[ch * 8]);
  }
#pragma unroll
  for (int p = 0; p < 8; p++) {
    int ch = t + 256 * p;
    int r = ch >> 3, gq = (ch & 7) ^ (r & 7);
    gl_lds16(Kb + kvbase + (size_t)r * 1024 + gq * 8, &Ks[ch * 8]);
  }
  // V transposed into Vt[d_orig][j]: stored position p -> orig ((p&3)<<4)|(p>>2)
#pragma unroll
  for (int p = 0; p < 8; p++) {
    int ch = t + 256 * p;
    int j = ch >> 3, d0 = (ch & 7) * 8;
    short8 vv = *(const short8*)(Vb + kvbase + (size_t)j * 1024 + d0);
#pragma unroll
    for (int ii = 0; ii < 8; ii++) {
      int pp = d0 + ii;
      int od = ((pp & 3) << 4) | (pp >> 2);
      Vt[od * 264 + j] = (ushort_t)vv[ii];
    }
  }
  __syncthreads();

  const int row = lane & 15, kg = (lane >> 4) * 8;
  const int cswz = (row & 7) << 3;
  f32x4 accs[4][4] = {};
#pragma unroll
  for (int kk = 0; kk < 64; kk += 32) {
    int cq = ((kk + kg) ^ cswz);
    short8 af[4], bfr[4];
#pragma unroll
    for (int m = 0; m < 4; m++) af[m] = *(const short8*)&Qs[(m * 16 + row) * 64 + cq];
#pragma unroll
    for (int n = 0; n < 4; n++)
      bfr[n] = *(const short8*)&Ks[(wv * 64 + n * 16 + row) * 64 + cq];
#pragma unroll
    for (int m = 0; m < 4; m++)
#pragma unroll
      for (int n = 0; n < 4; n++)
        accs[m][n] = __builtin_amdgcn_mfma_f32_16x16x32_bf16(af[m], bfr[n], accs[m][n], 0, 0, 0);
  }
  __syncthreads();

  {
    const int cr = (lane >> 4) * 4, cc = lane & 15;
#pragma unroll
    for (int m = 0; m < 4; m++)
#pragma unroll
      for (int n = 0; n < 4; n++)
#pragma unroll
        for (int j = 0; j < 4; j++)
          Sp[(m * 16 + cr + j) * 264 + wv * 64 + n * 16 + cc] = f2bf(accs[m][n][j]);
  }
  __syncthreads();

  {
    const int r = t >> 2, q = t & 3;
    const int base = r * 264 + q * 64;
    float ev[64];
#pragma unroll
    for (int p = 0; p < 8; p++) {
      short8 sv = *(const short8*)&Sp[base + p * 8];
#pragma unroll
      for (int i = 0; i < 8; i++) ev[p * 8 + i] = bf2f((ushort_t)sv[i]);
    }
    float mx = ev[0];
#pragma unroll
    for (int i = 1; i < 64; i++) mx = fmaxf(mx, ev[i]);
    mx = fmaxf(mx, __shfl_xor(mx, 1));
    mx = fmaxf(mx, __shfl_xor(mx, 2));
    float sum = 0.f;
#pragma unroll
    for (int i = 0; i < 64; i++) {
      ev[i] = __expf((ev[i] - mx) * 0.125f);
      sum += ev[i];
    }
    sum += __shfl_xor(sum, 1);
    sum += __shfl_xor(sum, 2);
    float inv = 1.f / sum;
#pragma unroll
    for (int p = 0; p < 8; p++) {
      short8 pv;
#pragma unroll
      for (int i = 0; i < 8; i++) pv[i] = (short)f2bf(ev[p * 8 + i] * inv);
      *(short8*)&Sp[base + p * 8] = pv;
    }
  }
  __syncthreads();

  {
    f32x4 acco[4] = {};
#pragma unroll
    for (int kt = 0; kt < 8; kt++) {
      short8 bfv = *(const short8*)&Vt[(wv * 16 + row) * 264 + kt * 32 + kg];
#pragma unroll
      for (int m = 0; m < 4; m++) {
        short8 af = *(const short8*)&Sp[(m * 16 + row) * 264 + kt * 32 + kg];
        acco[m] = __builtin_amdgcn_mfma_f32_16x16x32_bf16(af, bfv, acco[m], 0, 0, 0);
      }
    }
    const int cr = (lane >> 4) * 4, cc = lane & 15;
    size_t obase = ((size_t)(b * 32 + cch) * 64) * 1024 + hh * 64 + wv * 16 + cc;
#pragma unroll
    for (int m = 0; m < 4; m++)
#pragma unroll
      for (int j = 0; j < 4; j++)
        Ob[obase + (size_t)(m * 16 + cr + j) * 1024] = f2bf(acco[m][j]);
  }
}

// ---------------- residual-only prologue rows t < 63 ------------------------
__global__ void copy_prologue(const float* __restrict__ h, float* __restrict__ out) {
  int tt = blockIdx.x;  // 0..251
  int b = tt / 63, r = tt % 63;
  size_t idx = ((size_t)(b * 2048) + r) * 1024 + threadIdx.x * 4;
  *(f32x4*)&out[idx] = *(const f32x4*)&h[idx];
}

extern "C" void kernel_launch(void* const* d_in, const int* in_sizes, int n_in,
                              void* d_out, int out_size, void* d_ws, size_t ws_size,
                              hipStream_t stream) {
  const float* h    = (const float*)d_in[0];
  const float* e    = (const float*)d_in[1];
  const float* ln_g = (const float*)d_in[2];
  const float* ln_b = (const float*)d_in[3];
  const float* Wq   = (const float*)d_in[4];
  const float* bq   = (const float*)d_in[5];
  const float* Wk   = (const float*)d_in[6];
  const float* bk   = (const float*)d_in[7];
  const float* Wv   = (const float*)d_in[8];
  const float* bv   = (const float*)d_in[9];
  const float* Wo   = (const float*)d_in[10];
  const float* bo   = (const float*)d_in[11];
  float* out = (float*)d_out;

  char* ws = (char*)d_ws;
  const size_t MB = 1024 * 1024;
  ushort_t* WqT  = (ushort_t*)(ws + 0 * MB);
  ushort_t* WkT  = (ushort_t*)(ws + 2 * MB);   // WkT || WvT contiguous = BT[2048][1024]
  ushort_t* WvT  = (ushort_t*)(ws + 4 * MB);
  ushort_t* WoT  = (ushort_t*)(ws + 6 * MB);
  ushort_t* hb   = (ushort_t*)(ws + 8 * MB);    // 16 MB
  ushort_t* Qb   = (ushort_t*)(ws + 88 * MB);   // 16 MB
  ushort_t* Kbuf = (ushort_t*)(ws + 104 * MB);  // 64 MB
  ushort_t* Vbuf = (ushort_t*)(ws + 168 * MB);  // 64 MB
  ushort_t* Obuf = (ushort_t*)(ws + 232 * MB);  // 16 MB -> total 248 MB

  transpose_w4<<<dim3(32, 32, 4), 256, 0, stream>>>(Wq, Wk, Wv, Wo, WqT, WkT, WvT, WoT);

  ln_kernel<<<8192, 256, 0, stream>>>(h, ln_g, ln_b, hb);

  gemm_bt<0><<<512, 256, 0, stream>>>(hb, WqT, bq, Qb, nullptr, nullptr);
  gemm_kv256<<<1024, 512, 0, stream>>>(e, WkT, bk, bv, Kbuf, Vbuf);

  attn_kernel<<<dim3(16, 32, 4), 256, 0, stream>>>(Qb, Kbuf, Vbuf, Obuf);

  gemm_bt<1><<<512, 256, 0, stream>>>(Obuf, WoT, bo, nullptr, out, h);
  copy_prologue<<<252, 256, 0, stream>>>(h, out);
}

// Round 9
// 269.251 us; speedup vs baseline: 1.2404x; 1.2404x over previous
//
#include <hip/hip_runtime.h>

// RETRO chunked cross-attention, MI355X bf16 MFMA pipeline. Round 9:
//  - FUSED kv-projection + attention: each block = one (b,c) x head-pair.
//    GEMM (r6 kv256 2-phase loop, B = WkT-panel || WvT-panel) -> acc written
//    to LDS (K bias+pi-packed+XOR-swizzled; V bias+transposed, pi^-1 baked) ->
//    Q via global_load_lds -> verified attn body, 2 heads across 8 waves ->
//    O to global. Kills Kbuf/Vbuf HBM round-trip (256 MB) + attn dispatch.
//  - r8's f32-A fusion reverted (conv_bf16 restored; GEMM A = bf16).

typedef __attribute__((ext_vector_type(8))) short short8;
typedef __attribute__((ext_vector_type(4))) float f32x4;
typedef unsigned short ushort_t;
typedef unsigned long long u64;

__device__ inline ushort_t f2bf(float f) {
  union { float f; unsigned int u; } v; v.f = f;
  unsigned int u = v.u;
  return (ushort_t)((u + 0x7fffu + ((u >> 16) & 1u)) >> 16);
}
__device__ inline float bf2f(ushort_t s) {
  union { unsigned int u; float f; } v; v.u = ((unsigned int)s) << 16;
  return v.f;
}

__device__ inline void gl_lds16(const void* g, void* l) {
  __builtin_amdgcn_global_load_lds(
      (const __attribute__((address_space(1))) unsigned int*)g,
      (__attribute__((address_space(3))) unsigned int*)l, 16, 0, 0);
}

// ---------------- 4x weight transpose + bf16 cast: WT[n][k] = W[k][n] -------
__global__ void transpose_w4(const float* __restrict__ W0, const float* __restrict__ W1,
                             const float* __restrict__ W2, const float* __restrict__ W3,
                             ushort_t* __restrict__ T0, ushort_t* __restrict__ T1,
                             ushort_t* __restrict__ T2, ushort_t* __restrict__ T3) {
  __shared__ float tile[32][33];
  const int z = blockIdx.z;
  const float* W = (z == 0) ? W0 : (z == 1) ? W1 : (z == 2) ? W2 : W3;
  ushort_t* WT   = (z == 0) ? T0 : (z == 1) ? T1 : (z == 2) ? T2 : T3;
  int k0 = blockIdx.x * 32, n0 = blockIdx.y * 32;
  int c = threadIdx.x & 31, r = threadIdx.x >> 5;  // r in 0..7
#pragma unroll
  for (int p = 0; p < 4; p++)
    tile[r + p * 8][c] = W[(size_t)(k0 + r + p * 8) * 1024 + n0 + c];
  __syncthreads();
#pragma unroll
  for (int p = 0; p < 4; p++)
    WT[(size_t)(n0 + r + p * 8) * 1024 + k0 + c] = f2bf(tile[c][r + p * 8]);
}

// ---------------- shifted LayerNorm -> bf16 query rows ----------------------
__global__ void ln_kernel(const float* __restrict__ h, const float* __restrict__ g,
                          const float* __restrict__ bb, ushort_t* __restrict__ hb) {
  int row = blockIdx.x;            // 0..8191
  int b = row >> 11, jj = row & 2047;
  int t = threadIdx.x;
  ushort_t* dst = hb + (size_t)row * 1024;
  if (jj >= 1985) {
    ((unsigned int*)dst)[t] = 0u;
    ((unsigned int*)dst)[t + 256] = 0u;
    return;
  }
  const float* src = h + ((size_t)(b << 11) + jj + 63) * 1024;
  f32x4 x = *(const f32x4*)&src[t * 4];
  float s = x[0] + x[1] + x[2] + x[3];
  float sq = x[0]*x[0] + x[1]*x[1] + x[2]*x[2] + x[3]*x[3];
#pragma unroll
  for (int off = 32; off > 0; off >>= 1) {
    s  += __shfl_xor(s, off);
    sq += __shfl_xor(sq, off);
  }
  __shared__ float red[8];
  if ((t & 63) == 0) { red[(t >> 6) * 2] = s; red[(t >> 6) * 2 + 1] = sq; }
  __syncthreads();
  float sum = red[0] + red[2] + red[4] + red[6];
  float sumsq = red[1] + red[3] + red[5] + red[7];
  float mu = sum * (1.f / 1024.f);
  float var = sumsq * (1.f / 1024.f) - mu * mu;
  float rs = rsqrtf(var + 1e-5f);
  f32x4 gg = *(const f32x4*)&g[t * 4];
  f32x4 bv = *(const f32x4*)&bb[t * 4];
  ushort_t o0 = f2bf((x[0] - mu) * rs * gg[0] + bv[0]);
  ushort_t o1 = f2bf((x[1] - mu) * rs * gg[1] + bv[1]);
  ushort_t o2 = f2bf((x[2] - mu) * rs * gg[2] + bv[2]);
  ushort_t o3 = f2bf((x[3] - mu) * rs * gg[3] + bv[3]);
  u64 pack = (u64)o0 | ((u64)o1 << 16) | ((u64)o2 << 32) | ((u64)o3 << 48);
  *(u64*)&dst[t * 4] = pack;
}

// ---------------- f32 -> bf16 cast (vector) ---------------------------------
__global__ void conv_bf16(const float* __restrict__ s, ushort_t* __restrict__ d, int n8) {
  int i = blockIdx.x * 256 + threadIdx.x;
  if (i >= n8) return;
  const f32x4* sp = (const f32x4*)(s + (size_t)i * 8);
  f32x4 a = sp[0], b = sp[1];
  short8 o;
  o[0] = (short)f2bf(a[0]); o[1] = (short)f2bf(a[1]);
  o[2] = (short)f2bf(a[2]); o[3] = (short)f2bf(a[3]);
  o[4] = (short)f2bf(b[0]); o[5] = (short)f2bf(b[1]);
  o[6] = (short)f2bf(b[2]); o[7] = (short)f2bf(b[3]);
  *(short8*)(d + (size_t)i * 8) = o;
}

// ---------------- 128^2 GEMM, 2-phase fine schedule (r6) --------------------
template <int EPI>
__launch_bounds__(256, 2)
__global__ void gemm_bt(const ushort_t* __restrict__ A, const ushort_t* __restrict__ BT,
                        const float* __restrict__ bias, ushort_t* __restrict__ Cb,
                        float* __restrict__ Cf, const float* __restrict__ resid) {
  __shared__ __attribute__((aligned(16))) ushort_t lds[32768];  // 4 x (A 8KB + B 8KB)
  const int bid = blockIdx.x, cpx = gridDim.x >> 3;
  const int swz = (bid & 7) * cpx + (bid >> 3);
  const int tm = (swz >> 3) * 128, tn = (swz & 7) * 128;
  const int t = threadIdx.x, lane = t & 63, wv = t >> 6;
  const int wm = (wv >> 1) * 64, wn = (wv & 1) * 64;
  const int row16 = lane & 15, g = lane >> 4;

  const int c0 = t, c1 = t + 256;
  const int ra0 = c0 >> 2, sa0 = ((c0 & 3) ^ ((ra0 >> 1) & 3)) * 8;
  const int ra1 = c1 >> 2, sa1 = ((c1 & 3) ^ ((ra1 >> 1) & 3)) * 8;
  const ushort_t* Ag0 = A + (size_t)(tm + ra0) * 1024 + sa0;
  const ushort_t* Ag1 = A + (size_t)(tm + ra1) * 1024 + sa1;
  const ushort_t* Bg0 = BT + (size_t)(tn + ra0) * 1024 + sa0;
  const ushort_t* Bg1 = BT + (size_t)(tn + ra1) * 1024 + sa1;

#define STG_A(T) { ushort_t* L_ = lds + ((T) & 3) * 8192; const int k0_ = (T) * 32; \
    gl_lds16(Ag0 + k0_, L_ + c0 * 8); gl_lds16(Ag1 + k0_, L_ + c1 * 8); }
#define STG_B(T) { ushort_t* L_ = lds + ((T) & 3) * 8192; const int k0_ = (T) * 32; \
    gl_lds16(Bg0 + k0_, L_ + 4096 + c0 * 8); gl_lds16(Bg1 + k0_, L_ + 4096 + c1 * 8); }

  int aoff[4], boff[4];
#pragma unroll
  for (int m = 0; m < 4; m++) {
    int ra = wm + m * 16 + row16;
    aoff[m] = ra * 32 + (g ^ ((ra >> 1) & 3)) * 8;
  }
#pragma unroll
  for (int n = 0; n < 4; n++) {
    int rb = wn + n * 16 + row16;
    boff[n] = 4096 + rb * 32 + (g ^ ((rb >> 1) & 3)) * 8;
  }

  f32x4 acc[4][4] = {};
  STG_A(0); STG_B(0); STG_A(1); STG_B(1);
  for (int T = 0; T < 32; ++T) {
    const ushort_t* Lb = lds + (T & 3) * 8192;
    if (T < 31) { asm volatile("s_waitcnt vmcnt(4)" ::: "memory"); }
    else        { asm volatile("s_waitcnt vmcnt(0)" ::: "memory"); }
    __builtin_amdgcn_s_barrier();
    short8 af0, af1;
    short8 bfv[4];
#pragma unroll
    for (int n = 0; n < 4; n++) bfv[n] = *(const short8*)&Lb[boff[n]];
    af0 = *(const short8*)&Lb[aoff[0]];
    af1 = *(const short8*)&Lb[aoff[1]];
    if (T < 30) STG_A(T + 2);
    __builtin_amdgcn_s_barrier();
    asm volatile("s_waitcnt lgkmcnt(0)" ::: "memory");
    __builtin_amdgcn_sched_barrier(0);
    __builtin_amdgcn_s_setprio(1);
#pragma unroll
    for (int n = 0; n < 4; n++) {
      acc[0][n] = __builtin_amdgcn_mfma_f32_16x16x32_bf16(af0, bfv[n], acc[0][n], 0, 0, 0);
      acc[1][n] = __builtin_amdgcn_mfma_f32_16x16x32_bf16(af1, bfv[n], acc[1][n], 0, 0, 0);
    }
    __builtin_amdgcn_s_setprio(0);
    __builtin_amdgcn_s_barrier();
    af0 = *(const short8*)&Lb[aoff[2]];
    af1 = *(const short8*)&Lb[aoff[3]];
    if (T < 30) STG_B(T + 2);
    __builtin_amdgcn_s_barrier();
    asm volatile("s_waitcnt lgkmcnt(0)" ::: "memory");
    __builtin_amdgcn_sched_barrier(0);
    __builtin_amdgcn_s_setprio(1);
#pragma unroll
    for (int n = 0; n < 4; n++) {
      acc[2][n] = __builtin_amdgcn_mfma_f32_16x16x32_bf16(af0, bfv[n], acc[2][n], 0, 0, 0);
      acc[3][n] = __builtin_amdgcn_mfma_f32_16x16x32_bf16(af1, bfv[n], acc[3][n], 0, 0, 0);
    }
    __builtin_amdgcn_s_setprio(0);
  }
#undef STG_A
#undef STG_B

  const int cr = g * 4, cc = row16;
  if (EPI == 0) {
    const int cb = tn + wn;  // 64-col strip base
    float bsv[4];
#pragma unroll
    for (int n = 0; n < 4; n++) bsv[n] = bias[cb + n * 16 + cc];
#pragma unroll
    for (int m = 0; m < 4; m++) {
      int rbase = tm + wm + m * 16 + cr;
#pragma unroll
      for (int j = 0; j < 4; j++) {
        u64 pack = (u64)f2bf(acc[m][0][j] + bsv[0])
                 | ((u64)f2bf(acc[m][1][j] + bsv[1]) << 16)
                 | ((u64)f2bf(acc[m][2][j] + bsv[2]) << 32)
                 | ((u64)f2bf(acc[m][3][j] + bsv[3]) << 48);
        *(u64*)&Cb[(size_t)(rbase + j) * 1024 + cb + cc * 4] = pack;
      }
    }
  } else {
#pragma unroll
    for (int m = 0; m < 4; m++) {
#pragma unroll
      for (int n = 0; n < 4; n++) {
        int col = tn + wn + n * 16 + cc;
        float bsv = bias[col];
#pragma unroll
        for (int j = 0; j < 4; j++) {
          int rg = tm + wm + m * 16 + cr + j;
          float v = acc[m][n][j] + bsv;
          int b = rg >> 11, jj = rg & 2047;
          if (jj < 1985) {
            size_t oi = ((size_t)(b << 11) + jj + 63) * 1024 + col;
            Cf[oi] = v + resid[oi];
          }
        }
      }
    }
  }
}

// ---------------- FUSED: KV projection + attention --------------------------
// Block = (b,c) x head-pair hp. GEMM C[256x256] = e_bf[bc] @ [WkT_hp || WvT_hp]^T.
// acc -> LDS (K swizzled, V transposed) -> Q gl_lds -> attn (2 heads) -> Obuf.
// smem elems: [ring 65536 overlaid by] QA 0 | KA 4096 | QB 20480 | KB 24576 |
//             VtA 40960 | VtB 57856 | end 74752 (149504 B).
__launch_bounds__(512, 2)
__global__ void kv_attn(const ushort_t* __restrict__ A, const ushort_t* __restrict__ WkvT,
                        const float* __restrict__ bk, const float* __restrict__ bv,
                        const ushort_t* __restrict__ Qb, ushort_t* __restrict__ Ob) {
  __shared__ __attribute__((aligned(16))) ushort_t smem[74752];
  ushort_t* lds = smem;                          // GEMM ring: 4 x 16384 elems
  const int bid = blockIdx.x;                    // 1024 blocks
  const int swz = (bid & 7) * 128 + (bid >> 3);  // XCD chunk swizzle
  const int bc = swz >> 3, hp = swz & 7;         // (b,c) tile, head pair
  const int tm = bc * 256;
  const int t = threadIdx.x, lane = t & 63, wv = t >> 6;
  const int wm = wv >> 2, wn = wv & 3;
  const int row16 = lane & 15, g = lane >> 4;

  const int d1 = t + 512;
  const int ra0 = t >> 2, sa0 = ((t & 3) ^ ((ra0 >> 1) & 3)) * 8;
  const int ra1 = d1 >> 2, sa1 = ((d1 & 3) ^ ((ra1 >> 1) & 3)) * 8;
  const ushort_t* Ag0 = A + (size_t)(tm + ra0) * 1024 + sa0;
  const ushort_t* Ag1 = A + (size_t)(tm + ra1) * 1024 + sa1;
  // B rows 0..127 = WkT rows hp*128+ra0 ; rows 128..255 = WvT rows hp*128+(ra1-128)
  const ushort_t* Bg0 = WkvT + (size_t)(hp * 128 + ra0) * 1024 + sa0;
  const ushort_t* Bg1 = WkvT + (size_t)(1024 + hp * 128 + (ra1 - 128)) * 1024 + sa1;

#define STG256_A(T) { ushort_t* L_ = lds + ((T) & 3) * 16384; const int k0_ = (T) * 32; \
    gl_lds16(Ag0 + k0_, L_ + t * 8); gl_lds16(Ag1 + k0_, L_ + d1 * 8); }
#define STG256_B(T) { ushort_t* L_ = lds + ((T) & 3) * 16384; const int k0_ = (T) * 32; \
    gl_lds16(Bg0 + k0_, L_ + 8192 + t * 8); gl_lds16(Bg1 + k0_, L_ + 8192 + d1 * 8); }

  int aoff[8], boff[4];
#pragma unroll
  for (int m = 0; m < 8; m++) {
    int ra = wm * 128 + m * 16 + row16;
    aoff[m] = ra * 32 + (g ^ ((ra >> 1) & 3)) * 8;
  }
#pragma unroll
  for (int n = 0; n < 4; n++) {
    int rb = wn * 64 + n * 16 + row16;
    boff[n] = 8192 + rb * 32 + (g ^ ((rb >> 1) & 3)) * 8;
  }

  f32x4 acc[8][4] = {};
  STG256_A(0); STG256_B(0); STG256_A(1); STG256_B(1);
  for (int T = 0; T < 32; ++T) {
    const ushort_t* Lb = lds + (T & 3) * 16384;
    if (T < 31) { asm volatile("s_waitcnt vmcnt(4)" ::: "memory"); }
    else        { asm volatile("s_waitcnt vmcnt(0)" ::: "memory"); }
    __builtin_amdgcn_s_barrier();
    short8 af[4], bfv[4];
#pragma unroll
    for (int n = 0; n < 4; n++) bfv[n] = *(const short8*)&Lb[boff[n]];
#pragma unroll
    for (int m = 0; m < 4; m++) af[m] = *(const short8*)&Lb[aoff[m]];
    if (T < 30) STG256_A(T + 2);
    __builtin_amdgcn_s_barrier();
    asm volatile("s_waitcnt lgkmcnt(0)" ::: "memory");
    __builtin_amdgcn_sched_barrier(0);
    __builtin_amdgcn_s_setprio(1);
#pragma unroll
    for (int m = 0; m < 4; m++)
#pragma unroll
      for (int n = 0; n < 4; n++)
        acc[m][n] = __builtin_amdgcn_mfma_f32_16x16x32_bf16(af[m], bfv[n], acc[m][n], 0, 0, 0);
    __builtin_amdgcn_s_setprio(0);
    __builtin_amdgcn_s_barrier();
#pragma unroll
    for (int m = 0; m < 4; m++) af[m] = *(const short8*)&Lb[aoff[4 + m]];
    if (T < 30) STG256_B(T + 2);
    __builtin_amdgcn_s_barrier();
    asm volatile("s_waitcnt lgkmcnt(0)" ::: "memory");
    __builtin_amdgcn_sched_barrier(0);
    __builtin_amdgcn_s_setprio(1);
#pragma unroll
    for (int m = 0; m < 4; m++)
#pragma unroll
      for (int n = 0; n < 4; n++)
        acc[4 + m][n] = __builtin_amdgcn_mfma_f32_16x16x32_bf16(af[m], bfv[n], acc[4 + m][n], 0, 0, 0);
    __builtin_amdgcn_s_setprio(0);
  }
#undef STG256_A
#undef STG256_B

  __syncthreads();  // all ring reads done before overlaying attn regions

  // ---- acc -> LDS epilogue ----
  if (wn < 2) {
    // K head hb=wn: bias, pi-packed u64, attention XOR-swizzle (slot^=(krow&7))
    ushort_t* KsH = smem + (wn ? 24576 : 4096);
    float bsv[4];
#pragma unroll
    for (int n = 0; n < 4; n++) bsv[n] = bk[hp * 128 + wn * 64 + n * 16 + row16];
    const int slot = ((row16 >> 1) << 3) + (row16 & 1) * 4;  // pre-xor elem offset
#pragma unroll
    for (int m = 0; m < 8; m++) {
      int krow0 = wm * 128 + m * 16 + g * 4;
#pragma unroll
      for (int j = 0; j < 4; j++) {
        int krow = krow0 + j;
        u64 pack = (u64)f2bf(acc[m][0][j] + bsv[0])
                 | ((u64)f2bf(acc[m][1][j] + bsv[1]) << 16)
                 | ((u64)f2bf(acc[m][2][j] + bsv[2]) << 32)
                 | ((u64)f2bf(acc[m][3][j] + bsv[3]) << 48);
        int sl = ((row16 >> 1) ^ (krow & 7)) * 8 + (row16 & 1) * 4;
        *(u64*)&KsH[krow * 64 + sl] = pack;
      }
    }
    (void)slot;
  } else {
    // V head hb=wn-2: bias, transpose (Vt[d][kv], pi^-1 baked: od = n*16+row16)
    ushort_t* VtH = smem + 40960 + (wn & 1) * 16896;
    float bsv[4];
#pragma unroll
    for (int n = 0; n < 4; n++) bsv[n] = bv[hp * 128 + (wn - 2) * 64 + n * 16 + row16];
#pragma unroll
    for (int m = 0; m < 8; m++) {
      int krow0 = wm * 128 + m * 16 + g * 4;
#pragma unroll
      for (int n = 0; n < 4; n++) {
        int od = n * 16 + row16;
        u64 pack = (u64)f2bf(acc[m][n][0] + bsv[n])
                 | ((u64)f2bf(acc[m][n][1] + bsv[n]) << 16)
                 | ((u64)f2bf(acc[m][n][2] + bsv[n]) << 32)
                 | ((u64)f2bf(acc[m][n][3] + bsv[n]) << 48);
        *(u64*)&VtH[od * 264 + krow0] = pack;
      }
    }
  }
  // Q staging: head t>>8, 2 chunks/thread (pi-packed source, swizzled dest)
  {
    const int hb2 = t >> 8, tl = t & 255;
    ushort_t* QsH = smem + (hb2 ? 20480 : 0);
    size_t qbase = ((size_t)bc * 64) * 1024 + (hp * 2 + hb2) * 64;
    int ch = tl, r = ch >> 3, gq = (ch & 7) ^ (r & 7);
    gl_lds16(Qb + qbase + (size_t)r * 1024 + gq * 8, &QsH[ch * 8]);
    ch = tl + 256; r = ch >> 3; gq = (ch & 7) ^ (r & 7);
    gl_lds16(Qb + qbase + (size_t)r * 1024 + gq * 8, &QsH[ch * 8]);
  }
  __syncthreads();

  // ---- attention: threads [0,256) head A, [256,512) head B ----
  const int tl = t & 255, hb2 = t >> 8;
  const int wvL = tl >> 6, laneL = tl & 63;
  ushort_t* QsH = smem + (hb2 ? 20480 : 0);
  ushort_t* KsH = QsH + 4096;
  ushort_t* SpH = QsH;   // bf16 S/P [64][264] overlays Qs+Ks
  ushort_t* VtH = smem + 40960 + hb2 * 16896;

  const int rowA = laneL & 15, kgA = (laneL >> 4) * 8;
  const int cswz = (rowA & 7) << 3;
  f32x4 accs[4][4] = {};
#pragma unroll
  for (int kk = 0; kk < 64; kk += 32) {
    int cq = ((kk + kgA) ^ cswz);
    short8 af[4], bfr[4];
#pragma unroll
    for (int m = 0; m < 4; m++) af[m] = *(const short8*)&QsH[(m * 16 + rowA) * 64 + cq];
#pragma unroll
    for (int n = 0; n < 4; n++)
      bfr[n] = *(const short8*)&KsH[(wvL * 64 + n * 16 + rowA) * 64 + cq];
#pragma unroll
    for (int m = 0; m < 4; m++)
#pragma unroll
      for (int n = 0; n < 4; n++)
        accs[m][n] = __builtin_amdgcn_mfma_f32_16x16x32_bf16(af[m], bfr[n], accs[m][n], 0, 0, 0);
  }
  __syncthreads();  // Qs/Ks reads complete -> safe to overlay with S

  {
    const int cr = (laneL >> 4) * 4, cc = laneL & 15;
#pragma unroll
    for (int m = 0; m < 4; m++)
#pragma unroll
      for (int n = 0; n < 4; n++)
#pragma unroll
        for (int j = 0; j < 4; j++)
          SpH[(m * 16 + cr + j) * 264 + wvL * 64 + n * 16 + cc] = f2bf(accs[m][n][j]);
  }
  __syncthreads();

  {
    const int r = tl >> 2, q = tl & 3;
    const int base = r * 264 + q * 64;
    float ev[64];
#pragma unroll
    for (int p = 0; p < 8; p++) {
      short8 sv = *(const short8*)&SpH[base + p * 8];
#pragma unroll
      for (int i = 0; i < 8; i++) ev[p * 8 + i] = bf2f((ushort_t)sv[i]);
    }
    float mx = ev[0];
#pragma unroll
    for (int i = 1; i < 64; i++) mx = fmaxf(mx, ev[i]);
    mx = fmaxf(mx, __shfl_xor(mx, 1));
    mx = fmaxf(mx, __shfl_xor(mx, 2));
    float sum = 0.f;
#pragma unroll
    for (int i = 0; i < 64; i++) {
      ev[i] = __expf((ev[i] - mx) * 0.125f);
      sum += ev[i];
    }
    sum += __shfl_xor(sum, 1);
    sum += __shfl_xor(sum, 2);
    float inv = 1.f / sum;
#pragma unroll
    for (int p = 0; p < 8; p++) {
      short8 pv;
#pragma unroll
      for (int i = 0; i < 8; i++) pv[i] = (short)f2bf(ev[p * 8 + i] * inv);
      *(short8*)&SpH[base + p * 8] = pv;
    }
  }
  __syncthreads();

  {
    f32x4 acco[4] = {};
#pragma unroll
    for (int kt = 0; kt < 8; kt++) {
      short8 bfv = *(const short8*)&VtH[(wvL * 16 + rowA) * 264 + kt * 32 + kgA];
#pragma unroll
      for (int m = 0; m < 4; m++) {
        short8 af = *(const short8*)&SpH[(m * 16 + rowA) * 264 + kt * 32 + kgA];
        acco[m] = __builtin_amdgcn_mfma_f32_16x16x32_bf16(af, bfv, acco[m], 0, 0, 0);
      }
    }
    const int cr = (laneL >> 4) * 4, cc = laneL & 15;
    size_t obase = ((size_t)bc * 64) * 1024 + (hp * 2 + hb2) * 64 + wvL * 16 + cc;
#pragma unroll
    for (int m = 0; m < 4; m++)
#pragma unroll
      for (int j = 0; j < 4; j++)
        Ob[obase + (size_t)(m * 16 + cr + j) * 1024] = f2bf(acco[m][j]);
  }
}

// ---------------- residual-only prologue rows t < 63 ------------------------
__global__ void copy_prologue(const float* __restrict__ h, float* __restrict__ out) {
  int tt = blockIdx.x;  // 0..251
  int b = tt / 63, r = tt % 63;
  size_t idx = ((size_t)(b * 2048) + r) * 1024 + threadIdx.x * 4;
  *(f32x4*)&out[idx] = *(const f32x4*)&h[idx];
}

extern "C" void kernel_launch(void* const* d_in, const int* in_sizes, int n_in,
                              void* d_out, int out_size, void* d_ws, size_t ws_size,
                              hipStream_t stream) {
  const float* h    = (const float*)d_in[0];
  const float* e    = (const float*)d_in[1];
  const float* ln_g = (const float*)d_in[2];
  const float* ln_b = (const float*)d_in[3];
  const float* Wq   = (const float*)d_in[4];
  const float* bq   = (const float*)d_in[5];
  const float* Wk   = (const float*)d_in[6];
  const float* bk   = (const float*)d_in[7];
  const float* Wv   = (const float*)d_in[8];
  const float* bv   = (const float*)d_in[9];
  const float* Wo   = (const float*)d_in[10];
  const float* bo   = (const float*)d_in[11];
  float* out = (float*)d_out;

  char* ws = (char*)d_ws;
  const size_t MB = 1024 * 1024;
  ushort_t* WqT  = (ushort_t*)(ws + 0 * MB);
  ushort_t* WkT  = (ushort_t*)(ws + 2 * MB);   // WkT || WvT contiguous
  ushort_t* WvT  = (ushort_t*)(ws + 4 * MB);
  ushort_t* WoT  = (ushort_t*)(ws + 6 * MB);
  ushort_t* hb   = (ushort_t*)(ws + 8 * MB);    // 16 MB
  ushort_t* e_bf = (ushort_t*)(ws + 24 * MB);   // 64 MB
  ushort_t* Qb   = (ushort_t*)(ws + 88 * MB);   // 16 MB
  ushort_t* Obuf = (ushort_t*)(ws + 104 * MB);  // 16 MB -> total 120 MB

  transpose_w4<<<dim3(32, 32, 4), 256, 0, stream>>>(Wq, Wk, Wv, Wo, WqT, WkT, WvT, WoT);

  ln_kernel<<<8192, 256, 0, stream>>>(h, ln_g, ln_b, hb);
  conv_bf16<<<16384, 256, 0, stream>>>(e, e_bf, 4194304);  // 32768*1024/8

  gemm_bt<0><<<512, 256, 0, stream>>>(hb, WqT, bq, Qb, nullptr, nullptr);
  kv_attn<<<1024, 512, 0, stream>>>(e_bf, WkT, bk, bv, Qb, Obuf);

  gemm_bt<1><<<512, 256, 0, stream>>>(Obuf, WoT, bo, nullptr, out, h);
  copy_prologue<<<252, 256, 0, stream>>>(h, out);
}

// Round 10
// 258.415 us; speedup vs baseline: 1.2924x; 1.0419x over previous
//
#include <hip/hip_runtime.h>

// RETRO chunked cross-attention, MI355X bf16 MFMA pipeline. Round 10:
//  - kv_attn: Q prefetched at kernel start into LDS outside the GEMM ring
//    (new map: K 0..33792 | Vt 33792..67584 | Q 67584..75776 elems; ring
//    0..65536 overlaid by K/Vt only after the final ring barrier).
//  - prep_kernel: transpose_w4 + LN + conv_bf16 merged into one launch.
//  - copy_prologue folded into gemm_bt<1> (blocks >= 512).
//  - GEMM K-loops / attention bodies byte-identical to r9 (best verified).

typedef __attribute__((ext_vector_type(8))) short short8;
typedef __attribute__((ext_vector_type(4))) float f32x4;
typedef unsigned short ushort_t;
typedef unsigned long long u64;

__device__ inline ushort_t f2bf(float f) {
  union { float f; unsigned int u; } v; v.f = f;
  unsigned int u = v.u;
  return (ushort_t)((u + 0x7fffu + ((u >> 16) & 1u)) >> 16);
}
__device__ inline float bf2f(ushort_t s) {
  union { unsigned int u; float f; } v; v.u = ((unsigned int)s) << 16;
  return v.f;
}

__device__ inline void gl_lds16(const void* g, void* l) {
  __builtin_amdgcn_global_load_lds(
      (const __attribute__((address_space(1))) unsigned int*)g,
      (__attribute__((address_space(3))) unsigned int*)l, 16, 0, 0);
}

// ---------------- merged prep: 4x weight transpose | LN | f32->bf16 cast ----
// blocks [0,4096): transpose; [4096,12288): LN; [12288,28672): conv.
__global__ void prep_kernel(const float* __restrict__ W0, const float* __restrict__ W1,
                            const float* __restrict__ W2, const float* __restrict__ W3,
                            ushort_t* __restrict__ T0, ushort_t* __restrict__ T1,
                            ushort_t* __restrict__ T2, ushort_t* __restrict__ T3,
                            const float* __restrict__ h, const float* __restrict__ lg,
                            const float* __restrict__ lb, ushort_t* __restrict__ hb,
                            const float* __restrict__ e, ushort_t* __restrict__ e_bf) {
  __shared__ float tile[32][33];
  __shared__ float red[8];
  const int blk = blockIdx.x, t = threadIdx.x;

  if (blk < 4096) {  // ---- weight transpose + bf16: WT[n][k] = W[k][n]
    const int z = blk >> 10, xy = blk & 1023;
    const float* W = (z == 0) ? W0 : (z == 1) ? W1 : (z == 2) ? W2 : W3;
    ushort_t* WT   = (z == 0) ? T0 : (z == 1) ? T1 : (z == 2) ? T2 : T3;
    int k0 = (xy & 31) * 32, n0 = (xy >> 5) * 32;
    int c = t & 31, r = t >> 5;
#pragma unroll
    for (int p = 0; p < 4; p++)
      tile[r + p * 8][c] = W[(size_t)(k0 + r + p * 8) * 1024 + n0 + c];
    __syncthreads();
#pragma unroll
    for (int p = 0; p < 4; p++)
      WT[(size_t)(n0 + r + p * 8) * 1024 + k0 + c] = f2bf(tile[c][r + p * 8]);
    return;
  }
  if (blk < 12288) {  // ---- shifted LayerNorm -> bf16 query rows
    int row = blk - 4096;            // 0..8191
    int b = row >> 11, jj = row & 2047;
    ushort_t* dst = hb + (size_t)row * 1024;
    if (jj >= 1985) {
      ((unsigned int*)dst)[t] = 0u;
      ((unsigned int*)dst)[t + 256] = 0u;
      return;
    }
    const float* src = h + ((size_t)(b << 11) + jj + 63) * 1024;
    f32x4 x = *(const f32x4*)&src[t * 4];
    float s = x[0] + x[1] + x[2] + x[3];
    float sq = x[0]*x[0] + x[1]*x[1] + x[2]*x[2] + x[3]*x[3];
#pragma unroll
    for (int off = 32; off > 0; off >>= 1) {
      s  += __shfl_xor(s, off);
      sq += __shfl_xor(sq, off);
    }
    if ((t & 63) == 0) { red[(t >> 6) * 2] = s; red[(t >> 6) * 2 + 1] = sq; }
    __syncthreads();
    float sum = red[0] + red[2] + red[4] + red[6];
    float sumsq = red[1] + red[3] + red[5] + red[7];
    float mu = sum * (1.f / 1024.f);
    float var = sumsq * (1.f / 1024.f) - mu * mu;
    float rs = rsqrtf(var + 1e-5f);
    f32x4 gg = *(const f32x4*)&lg[t * 4];
    f32x4 bv = *(const f32x4*)&lb[t * 4];
    ushort_t o0 = f2bf((x[0] - mu) * rs * gg[0] + bv[0]);
    ushort_t o1 = f2bf((x[1] - mu) * rs * gg[1] + bv[1]);
    ushort_t o2 = f2bf((x[2] - mu) * rs * gg[2] + bv[2]);
    ushort_t o3 = f2bf((x[3] - mu) * rs * gg[3] + bv[3]);
    u64 pack = (u64)o0 | ((u64)o1 << 16) | ((u64)o2 << 32) | ((u64)o3 << 48);
    *(u64*)&dst[t * 4] = pack;
    return;
  }
  // ---- f32 -> bf16 cast
  {
    int i = (blk - 12288) * 256 + t;   // < 4194304
    const f32x4* sp = (const f32x4*)(e + (size_t)i * 8);
    f32x4 a = sp[0], b = sp[1];
    short8 o;
    o[0] = (short)f2bf(a[0]); o[1] = (short)f2bf(a[1]);
    o[2] = (short)f2bf(a[2]); o[3] = (short)f2bf(a[3]);
    o[4] = (short)f2bf(b[0]); o[5] = (short)f2bf(b[1]);
    o[6] = (short)f2bf(b[2]); o[7] = (short)f2bf(b[3]);
    *(short8*)(e_bf + (size_t)i * 8) = o;
  }
}

// ---------------- 128^2 GEMM, 2-phase fine schedule (r6) --------------------
// EPI 0: bf16 out, pi-packed 8B stores (Q path), grid 512.
// EPI 1: f32 out + residual + shifted store (O path), grid 764
//        (blocks >= 512 copy the residual-only prologue rows).
template <int EPI>
__launch_bounds__(256, 2)
__global__ void gemm_bt(const ushort_t* __restrict__ A, const ushort_t* __restrict__ BT,
                        const float* __restrict__ bias, ushort_t* __restrict__ Cb,
                        float* __restrict__ Cf, const float* __restrict__ resid) {
  const int bid = blockIdx.x;
  if (EPI == 1 && bid >= 512) {   // prologue rows t < 63
    int tt = bid - 512;           // 0..251
    int b = tt / 63, r = tt % 63;
    size_t idx = ((size_t)(b * 2048) + r) * 1024 + threadIdx.x * 4;
    *(f32x4*)&Cf[idx] = *(const f32x4*)&resid[idx];
    return;
  }
  __shared__ __attribute__((aligned(16))) ushort_t lds[32768];  // 4 x (A 8KB + B 8KB)
  const int cpx = 64;             // 512 GEMM blocks / 8 XCDs
  const int swz = (bid & 7) * cpx + (bid >> 3);
  const int tm = (swz >> 3) * 128, tn = (swz & 7) * 128;
  const int t = threadIdx.x, lane = t & 63, wv = t >> 6;
  const int wm = (wv >> 1) * 64, wn = (wv & 1) * 64;
  const int row16 = lane & 15, g = lane >> 4;

  const int c0 = t, c1 = t + 256;
  const int ra0 = c0 >> 2, sa0 = ((c0 & 3) ^ ((ra0 >> 1) & 3)) * 8;
  const int ra1 = c1 >> 2, sa1 = ((c1 & 3) ^ ((ra1 >> 1) & 3)) * 8;
  const ushort_t* Ag0 = A + (size_t)(tm + ra0) * 1024 + sa0;
  const ushort_t* Ag1 = A + (size_t)(tm + ra1) * 1024 + sa1;
  const ushort_t* Bg0 = BT + (size_t)(tn + ra0) * 1024 + sa0;
  const ushort_t* Bg1 = BT + (size_t)(tn + ra1) * 1024 + sa1;

#define STG_A(T) { ushort_t* L_ = lds + ((T) & 3) * 8192; const int k0_ = (T) * 32; \
    gl_lds16(Ag0 + k0_, L_ + c0 * 8); gl_lds16(Ag1 + k0_, L_ + c1 * 8); }
#define STG_B(T) { ushort_t* L_ = lds + ((T) & 3) * 8192; const int k0_ = (T) * 32; \
    gl_lds16(Bg0 + k0_, L_ + 4096 + c0 * 8); gl_lds16(Bg1 + k0_, L_ + 4096 + c1 * 8); }

  int aoff[4], boff[4];
#pragma unroll
  for (int m = 0; m < 4; m++) {
    int ra = wm + m * 16 + row16;
    aoff[m] = ra * 32 + (g ^ ((ra >> 1) & 3)) * 8;
  }
#pragma unroll
  for (int n = 0; n < 4; n++) {
    int rb = wn + n * 16 + row16;
    boff[n] = 4096 + rb * 32 + (g ^ ((rb >> 1) & 3)) * 8;
  }

  f32x4 acc[4][4] = {};
  STG_A(0); STG_B(0); STG_A(1); STG_B(1);
  for (int T = 0; T < 32; ++T) {
    const ushort_t* Lb = lds + (T & 3) * 8192;
    if (T < 31) { asm volatile("s_waitcnt vmcnt(4)" ::: "memory"); }
    else        { asm volatile("s_waitcnt vmcnt(0)" ::: "memory"); }
    __builtin_amdgcn_s_barrier();
    short8 af0, af1;
    short8 bfv[4];
#pragma unroll
    for (int n = 0; n < 4; n++) bfv[n] = *(const short8*)&Lb[boff[n]];
    af0 = *(const short8*)&Lb[aoff[0]];
    af1 = *(const short8*)&Lb[aoff[1]];
    if (T < 30) STG_A(T + 2);
    __builtin_amdgcn_s_barrier();
    asm volatile("s_waitcnt lgkmcnt(0)" ::: "memory");
    __builtin_amdgcn_sched_barrier(0);
    __builtin_amdgcn_s_setprio(1);
#pragma unroll
    for (int n = 0; n < 4; n++) {
      acc[0][n] = __builtin_amdgcn_mfma_f32_16x16x32_bf16(af0, bfv[n], acc[0][n], 0, 0, 0);
      acc[1][n] = __builtin_amdgcn_mfma_f32_16x16x32_bf16(af1, bfv[n], acc[1][n], 0, 0, 0);
    }
    __builtin_amdgcn_s_setprio(0);
    __builtin_amdgcn_s_barrier();
    af0 = *(const short8*)&Lb[aoff[2]];
    af1 = *(const short8*)&Lb[aoff[3]];
    if (T < 30) STG_B(T + 2);
    __builtin_amdgcn_s_barrier();
    asm volatile("s_waitcnt lgkmcnt(0)" ::: "memory");
    __builtin_amdgcn_sched_barrier(0);
    __builtin_amdgcn_s_setprio(1);
#pragma unroll
    for (int n = 0; n < 4; n++) {
      acc[2][n] = __builtin_amdgcn_mfma_f32_16x16x32_bf16(af0, bfv[n], acc[2][n], 0, 0, 0);
      acc[3][n] = __builtin_amdgcn_mfma_f32_16x16x32_bf16(af1, bfv[n], acc[3][n], 0, 0, 0);
    }
    __builtin_amdgcn_s_setprio(0);
  }
#undef STG_A
#undef STG_B

  const int cr = g * 4, cc = row16;
  if (EPI == 0) {
    const int cb = tn + wn;  // 64-col strip base
    float bsv[4];
#pragma unroll
    for (int n = 0; n < 4; n++) bsv[n] = bias[cb + n * 16 + cc];
#pragma unroll
    for (int m = 0; m < 4; m++) {
      int rbase = tm + wm + m * 16 + cr;
#pragma unroll
      for (int j = 0; j < 4; j++) {
        u64 pack = (u64)f2bf(acc[m][0][j] + bsv[0])
                 | ((u64)f2bf(acc[m][1][j] + bsv[1]) << 16)
                 | ((u64)f2bf(acc[m][2][j] + bsv[2]) << 32)
                 | ((u64)f2bf(acc[m][3][j] + bsv[3]) << 48);
        *(u64*)&Cb[(size_t)(rbase + j) * 1024 + cb + cc * 4] = pack;
      }
    }
  } else {
#pragma unroll
    for (int m = 0; m < 4; m++) {
#pragma unroll
      for (int n = 0; n < 4; n++) {
        int col = tn + wn + n * 16 + cc;
        float bsv = bias[col];
#pragma unroll
        for (int j = 0; j < 4; j++) {
          int rg = tm + wm + m * 16 + cr + j;
          float v = acc[m][n][j] + bsv;
          int b = rg >> 11, jj = rg & 2047;
          if (jj < 1985) {
            size_t oi = ((size_t)(b << 11) + jj + 63) * 1024 + col;
            Cf[oi] = v + resid[oi];
          }
        }
      }
    }
  }
}

// ---------------- FUSED: KV projection + attention --------------------------
// Block = (b,c) x head-pair hp. GEMM C[256x256] = e_bf[bc] @ [WkT_hp || WvT_hp]^T.
// LDS map (elems): ring 0..65536 | KA 0..16896 | KB 16896..33792 |
//   VtA 33792..50688 | VtB 50688..67584 | QA 67584..71680 | QB 71680..75776.
// Q prefetched at kernel start (region outside ring). K/Vt written after the
// final ring barrier. S overlays the K region (after QK^T reads).
__launch_bounds__(512, 2)
__global__ void kv_attn(const ushort_t* __restrict__ A, const ushort_t* __restrict__ WkvT,
                        const float* __restrict__ bk, const float* __restrict__ bv,
                        const ushort_t* __restrict__ Qb, ushort_t* __restrict__ Ob) {
  __shared__ __attribute__((aligned(16))) ushort_t smem[75776];
  ushort_t* lds = smem;                          // GEMM ring: 4 x 16384 elems
  const int bid = blockIdx.x;                    // 1024 blocks
  const int swz = (bid & 7) * 128 + (bid >> 3);  // XCD chunk swizzle
  const int bc = swz >> 3, hp = swz & 7;         // (b,c) tile, head pair
  const int tm = bc * 256;
  const int t = threadIdx.x, lane = t & 63, wv = t >> 6;
  const int wm = wv >> 2, wn = wv & 3;
  const int row16 = lane & 15, g = lane >> 4;

  // ---- Q prefetch (issued first; lands under the GEMM loop) ----
  {
    const int hb2q = t >> 8, tlq = t & 255;
    ushort_t* QsH = smem + 67584 + hb2q * 4096;
    size_t qbase = ((size_t)bc * 64) * 1024 + (hp * 2 + hb2q) * 64;
    int ch = tlq, r = ch >> 3, gq = (ch & 7) ^ (r & 7);
    gl_lds16(Qb + qbase + (size_t)r * 1024 + gq * 8, &QsH[ch * 8]);
    ch = tlq + 256; r = ch >> 3; gq = (ch & 7) ^ (r & 7);
    gl_lds16(Qb + qbase + (size_t)r * 1024 + gq * 8, &QsH[ch * 8]);
  }

  const int d1 = t + 512;
  const int ra0 = t >> 2, sa0 = ((t & 3) ^ ((ra0 >> 1) & 3)) * 8;
  const int ra1 = d1 >> 2, sa1 = ((d1 & 3) ^ ((ra1 >> 1) & 3)) * 8;
  const ushort_t* Ag0 = A + (size_t)(tm + ra0) * 1024 + sa0;
  const ushort_t* Ag1 = A + (size_t)(tm + ra1) * 1024 + sa1;
  const ushort_t* Bg0 = WkvT + (size_t)(hp * 128 + ra0) * 1024 + sa0;
  const ushort_t* Bg1 = WkvT + (size_t)(1024 + hp * 128 + (ra1 - 128)) * 1024 + sa1;

#define STG256_A(T) { ushort_t* L_ = lds + ((T) & 3) * 16384; const int k0_ = (T) * 32; \
    gl_lds16(Ag0 + k0_, L_ + t * 8); gl_lds16(Ag1 + k0_, L_ + d1 * 8); }
#define STG256_B(T) { ushort_t* L_ = lds + ((T) & 3) * 16384; const int k0_ = (T) * 32; \
    gl_lds16(Bg0 + k0_, L_ + 8192 + t * 8); gl_lds16(Bg1 + k0_, L_ + 8192 + d1 * 8); }

  int aoff[8], boff[4];
#pragma unroll
  for (int m = 0; m < 8; m++) {
    int ra = wm * 128 + m * 16 + row16;
    aoff[m] = ra * 32 + (g ^ ((ra >> 1) & 3)) * 8;
  }
#pragma unroll
  for (int n = 0; n < 4; n++) {
    int rb = wn * 64 + n * 16 + row16;
    boff[n] = 8192 + rb * 32 + (g ^ ((rb >> 1) & 3)) * 8;
  }

  f32x4 acc[8][4] = {};
  STG256_A(0); STG256_B(0); STG256_A(1); STG256_B(1);
  for (int T = 0; T < 32; ++T) {
    const ushort_t* Lb = lds + (T & 3) * 16384;
    if (T < 31) { asm volatile("s_waitcnt vmcnt(4)" ::: "memory"); }
    else        { asm volatile("s_waitcnt vmcnt(0)" ::: "memory"); }
    __builtin_amdgcn_s_barrier();
    short8 af[4], bfv[4];
#pragma unroll
    for (int n = 0; n < 4; n++) bfv[n] = *(const short8*)&Lb[boff[n]];
#pragma unroll
    for (int m = 0; m < 4; m++) af[m] = *(const short8*)&Lb[aoff[m]];
    if (T < 30) STG256_A(T + 2);
    __builtin_amdgcn_s_barrier();
    asm volatile("s_waitcnt lgkmcnt(0)" ::: "memory");
    __builtin_amdgcn_sched_barrier(0);
    __builtin_amdgcn_s_setprio(1);
#pragma unroll
    for (int m = 0; m < 4; m++)
#pragma unroll
      for (int n = 0; n < 4; n++)
        acc[m][n] = __builtin_amdgcn_mfma_f32_16x16x32_bf16(af[m], bfv[n], acc[m][n], 0, 0, 0);
    __builtin_amdgcn_s_setprio(0);
    __builtin_amdgcn_s_barrier();
#pragma unroll
    for (int m = 0; m < 4; m++) af[m] = *(const short8*)&Lb[aoff[4 + m]];
    if (T < 30) STG256_B(T + 2);
    __builtin_amdgcn_s_barrier();
    asm volatile("s_waitcnt lgkmcnt(0)" ::: "memory");
    __builtin_amdgcn_sched_barrier(0);
    __builtin_amdgcn_s_setprio(1);
#pragma unroll
    for (int m = 0; m < 4; m++)
#pragma unroll
      for (int n = 0; n < 4; n++)
        acc[4 + m][n] = __builtin_amdgcn_mfma_f32_16x16x32_bf16(af[m], bfv[n], acc[4 + m][n], 0, 0, 0);
    __builtin_amdgcn_s_setprio(0);
  }
#undef STG256_A
#undef STG256_B

  __syncthreads();  // all ring reads done before overlaying K/Vt regions

  // ---- acc -> LDS epilogue ----
  if (wn < 2) {
    // K head hb=wn: bias, pi-packed u64, attention XOR-swizzle
    ushort_t* KsH = smem + wn * 16896;
    float bsv[4];
#pragma unroll
    for (int n = 0; n < 4; n++) bsv[n] = bk[hp * 128 + wn * 64 + n * 16 + row16];
#pragma unroll
    for (int m = 0; m < 8; m++) {
      int krow0 = wm * 128 + m * 16 + g * 4;
#pragma unroll
      for (int j = 0; j < 4; j++) {
        int krow = krow0 + j;
        u64 pack = (u64)f2bf(acc[m][0][j] + bsv[0])
                 | ((u64)f2bf(acc[m][1][j] + bsv[1]) << 16)
                 | ((u64)f2bf(acc[m][2][j] + bsv[2]) << 32)
                 | ((u64)f2bf(acc[m][3][j] + bsv[3]) << 48);
        int sl = ((row16 >> 1) ^ (krow & 7)) * 8 + (row16 & 1) * 4;
        *(u64*)&KsH[krow * 64 + sl] = pack;
      }
    }
  } else {
    // V head hb=wn-2: bias, transpose (Vt[d][kv], pi^-1 baked: od = n*16+row16)
    ushort_t* VtH = smem + 33792 + (wn & 1) * 16896;
    float bsv[4];
#pragma unroll
    for (int n = 0; n < 4; n++) bsv[n] = bv[hp * 128 + (wn - 2) * 64 + n * 16 + row16];
#pragma unroll
    for (int m = 0; m < 8; m++) {
      int krow0 = wm * 128 + m * 16 + g * 4;
#pragma unroll
      for (int n = 0; n < 4; n++) {
        int od = n * 16 + row16;
        u64 pack = (u64)f2bf(acc[m][n][0] + bsv[n])
                 | ((u64)f2bf(acc[m][n][1] + bsv[n]) << 16)
                 | ((u64)f2bf(acc[m][n][2] + bsv[n]) << 32)
                 | ((u64)f2bf(acc[m][n][3] + bsv[n]) << 48);
        *(u64*)&VtH[od * 264 + krow0] = pack;
      }
    }
  }
  __syncthreads();

  // ---- attention: threads [0,256) head A, [256,512) head B ----
  const int tl = t & 255, hb2 = t >> 8;
  const int wvL = tl >> 6, laneL = tl & 63;
  ushort_t* QsH = smem + 67584 + hb2 * 4096;
  ushort_t* KsH = smem + hb2 * 16896;
  ushort_t* SpH = KsH;   // bf16 S/P [64][264] overlays Ks after QK^T
  ushort_t* VtH = smem + 33792 + hb2 * 16896;

  const int rowA = laneL & 15, kgA = (laneL >> 4) * 8;
  const int cswz = (rowA & 7) << 3;
  f32x4 accs[4][4] = {};
#pragma unroll
  for (int kk = 0; kk < 64; kk += 32) {
    int cq = ((kk + kgA) ^ cswz);
    short8 af[4], bfr[4];
#pragma unroll
    for (int m = 0; m < 4; m++) af[m] = *(const short8*)&QsH[(m * 16 + rowA) * 64 + cq];
#pragma unroll
    for (int n = 0; n < 4; n++)
      bfr[n] = *(const short8*)&KsH[(wvL * 64 + n * 16 + rowA) * 64 + cq];
#pragma unroll
    for (int m = 0; m < 4; m++)
#pragma unroll
      for (int n = 0; n < 4; n++)
        accs[m][n] = __builtin_amdgcn_mfma_f32_16x16x32_bf16(af[m], bfr[n], accs[m][n], 0, 0, 0);
  }
  __syncthreads();  // Ks reads complete -> safe to overlay with S

  {
    const int cr = (laneL >> 4) * 4, cc = laneL & 15;
#pragma unroll
    for (int m = 0; m < 4; m++)
#pragma unroll
      for (int n = 0; n < 4; n++)
#pragma unroll
        for (int j = 0; j < 4; j++)
          SpH[(m * 16 + cr + j) * 264 + wvL * 64 + n * 16 + cc] = f2bf(accs[m][n][j]);
  }
  __syncthreads();

  {
    const int r = tl >> 2, q = tl & 3;
    const int base = r * 264 + q * 64;
    float ev[64];
#pragma unroll
    for (int p = 0; p < 8; p++) {
      short8 sv = *(const short8*)&SpH[base + p * 8];
#pragma unroll
      for (int i = 0; i < 8; i++) ev[p * 8 + i] = bf2f((ushort_t)sv[i]);
    }
    float mx = ev[0];
#pragma unroll
    for (int i = 1; i < 64; i++) mx = fmaxf(mx, ev[i]);
    mx = fmaxf(mx, __shfl_xor(mx, 1));
    mx = fmaxf(mx, __shfl_xor(mx, 2));
    float sum = 0.f;
#pragma unroll
    for (int i = 0; i < 64; i++) {
      ev[i] = __expf((ev[i] - mx) * 0.125f);
      sum += ev[i];
    }
    sum += __shfl_xor(sum, 1);
    sum += __shfl_xor(sum, 2);
    float inv = 1.f / sum;
#pragma unroll
    for (int p = 0; p < 8; p++) {
      short8 pv;
#pragma unroll
      for (int i = 0; i < 8; i++) pv[i] = (short)f2bf(ev[p * 8 + i] * inv);
      *(short8*)&SpH[base + p * 8] = pv;
    }
  }
  __syncthreads();

  {
    f32x4 acco[4] = {};
#pragma unroll
    for (int kt = 0; kt < 8; kt++) {
      short8 bfv = *(const short8*)&VtH[(wvL * 16 + rowA) * 264 + kt * 32 + kgA];
#pragma unroll
      for (int m = 0; m < 4; m++) {
        short8 af = *(const short8*)&SpH[(m * 16 + rowA) * 264 + kt * 32 + kgA];
        acco[m] = __builtin_amdgcn_mfma_f32_16x16x32_bf16(af, bfv, acco[m], 0, 0, 0);
      }
    }
    const int cr = (laneL >> 4) * 4, cc = laneL & 15;
    size_t obase = ((size_t)bc * 64) * 1024 + (hp * 2 + hb2) * 64 + wvL * 16 + cc;
#pragma unroll
    for (int m = 0; m < 4; m++)
#pragma unroll
      for (int j = 0; j < 4; j++)
        Ob[obase + (size_t)(m * 16 + cr + j) * 1024] = f2bf(acco[m][j]);
  }
}

extern "C" void kernel_launch(void* const* d_in, const int* in_sizes, int n_in,
                              void* d_out, int out_size, void* d_ws, size_t ws_size,
                              hipStream_t stream) {
  const float* h    = (const float*)d_in[0];
  const float* e    = (const float*)d_in[1];
  const float* ln_g = (const float*)d_in[2];
  const float* ln_b = (const float*)d_in[3];
  const float* Wq   = (const float*)d_in[4];
  const float* bq   = (const float*)d_in[5];
  const float* Wk   = (const float*)d_in[6];
  const float* bk   = (const float*)d_in[7];
  const float* Wv   = (const float*)d_in[8];
  const float* bv   = (const float*)d_in[9];
  const float* Wo   = (const float*)d_in[10];
  const float* bo   = (const float*)d_in[11];
  float* out = (float*)d_out;

  char* ws = (char*)d_ws;
  const size_t MB = 1024 * 1024;
  ushort_t* WqT  = (ushort_t*)(ws + 0 * MB);
  ushort_t* WkT  = (ushort_t*)(ws + 2 * MB);   // WkT || WvT contiguous
  ushort_t* WvT  = (ushort_t*)(ws + 4 * MB);
  ushort_t* WoT  = (ushort_t*)(ws + 6 * MB);
  ushort_t* hb   = (ushort_t*)(ws + 8 * MB);    // 16 MB
  ushort_t* e_bf = (ushort_t*)(ws + 24 * MB);   // 64 MB
  ushort_t* Qb   = (ushort_t*)(ws + 88 * MB);   // 16 MB
  ushort_t* Obuf = (ushort_t*)(ws + 104 * MB);  // 16 MB -> total 120 MB

  prep_kernel<<<28672, 256, 0, stream>>>(Wq, Wk, Wv, Wo, WqT, WkT, WvT, WoT,
                                         h, ln_g, ln_b, hb, e, e_bf);

  gemm_bt<0><<<512, 256, 0, stream>>>(hb, WqT, bq, Qb, nullptr, nullptr);
  kv_attn<<<1024, 512, 0, stream>>>(e_bf, WkT, bk, bv, Qb, Obuf);

  gemm_bt<1><<<764, 256, 0, stream>>>(Obuf, WoT, bo, nullptr, out, h);
}